// Round 12
// baseline (375.216 us; speedup 1.0000x reference)
//
#include <hip/hip_runtime.h>
#include <hip/hip_bf16.h>
#include <stdint.h>

#define B_SZ   4096
#define TWO_B  8192
#define D_DIM  2048
#define N_TOT  15000000
#define RHO    0.8f
#define NT     32         // 2048 / 64 K-tiles (fp8, BK=64)
#define NJOB   1024       // main jobs: cells 0..1023 (C-major over upper-tri 128x256 cells)
#define NSLV   256        // 32 remaining cells (C=31, R=32..63) x 8 slivers of 16x256
#define NBLK   1280       // NJOB + NSLV
#define INV_SC (1.0f/256.0f)   // undo the 16x16 input pre-scale

typedef __attribute__((ext_vector_type(4))) float f32x4;
typedef float4 __attribute__((aligned(4))) float4u;

// ---------- helpers ----------
__device__ __forceinline__ float waveReduceSum(float v) {
#pragma unroll
    for (int off = 32; off >= 1; off >>= 1) v += __shfl_down(v, off, 64);
    return v;
}
__device__ __forceinline__ void gload_lds16(const void* g, void* l) {
    __builtin_amdgcn_global_load_lds(
        (const __attribute__((address_space(1))) void*)(uintptr_t)g,
        (__attribute__((address_space(3))) void*)(uintptr_t)l,
        16, 0, 0);
}
__device__ __forceinline__ unsigned pk4(float a, float b, float c, float d) {
    int r = 0;
    r = __builtin_amdgcn_cvt_pk_fp8_f32(a, b, r, false);   // bytes 0,1
    r = __builtin_amdgcn_cvt_pk_fp8_f32(c, d, r, true);    // bytes 2,3
    return (unsigned)r;
}

// ---------- kernel 1: paired normalize -> fp8 e4m3 (x16), + pos dot, + zero E/F/loss ----------
__global__ __launch_bounds__(256) void knorm2(const float* __restrict__ feat,
                                              unsigned char* __restrict__ f8,
                                              float* __restrict__ posdot,
                                              float* __restrict__ EF,
                                              float* __restrict__ out) {
    int i = blockIdx.x;           // [0, B)
    int tid = threadIdx.x;
    // fused zeroing: E and F (2*TWO_B floats = 4096 float4) by blocks 0..15; loss by block 16
    if (i < 16) {
        float4 z = make_float4(0.f, 0.f, 0.f, 0.f);
        reinterpret_cast<float4*>(EF)[i * 256 + tid] = z;
    }
    if (i == 16 && tid == 0) out[0] = 0.f;

    const float4* ra = reinterpret_cast<const float4*>(feat + (size_t)i * D_DIM);
    const float4* rb = reinterpret_cast<const float4*>(feat + (size_t)(i + B_SZ) * D_DIM);
    float4 a0 = ra[tid * 2], a1 = ra[tid * 2 + 1];
    float4 b0 = rb[tid * 2], b1 = rb[tid * 2 + 1];
    float sa = a0.x*a0.x + a0.y*a0.y + a0.z*a0.z + a0.w*a0.w
             + a1.x*a1.x + a1.y*a1.y + a1.z*a1.z + a1.w*a1.w;
    float sb = b0.x*b0.x + b0.y*b0.y + b0.z*b0.z + b0.w*b0.w
             + b1.x*b1.x + b1.y*b1.y + b1.z*b1.z + b1.w*b1.w;
    float dp = a0.x*b0.x + a0.y*b0.y + a0.z*b0.z + a0.w*b0.w
             + a1.x*b1.x + a1.y*b1.y + a1.z*b1.z + a1.w*b1.w;
    sa = waveReduceSum(sa);
    sb = waveReduceSum(sb);
    dp = waveReduceSum(dp);
    __shared__ float wsum[3][4];
    if ((tid & 63) == 0) {
        int wv = tid >> 6;
        wsum[0][wv] = sa; wsum[1][wv] = sb; wsum[2][wv] = dp;
    }
    __syncthreads();
    float ta = wsum[0][0] + wsum[0][1] + wsum[0][2] + wsum[0][3];
    float tb = wsum[1][0] + wsum[1][1] + wsum[1][2] + wsum[1][3];
    float td = wsum[2][0] + wsum[2][1] + wsum[2][2] + wsum[2][3];
    float ia = 1.0f / fmaxf(sqrtf(ta), 1e-12f);
    float ib = 1.0f / fmaxf(sqrtf(tb), 1e-12f);
    if (tid == 0) posdot[i] = td * ia * ib;
    float xa = ia * 16.0f, xb = ib * 16.0f;   // pre-scale for e4m3 dynamic range
    uint2 oa, ob;
    oa.x = pk4(a0.x * xa, a0.y * xa, a0.z * xa, a0.w * xa);
    oa.y = pk4(a1.x * xa, a1.y * xa, a1.z * xa, a1.w * xa);
    ob.x = pk4(b0.x * xb, b0.y * xb, b0.z * xb, b0.w * xb);
    ob.y = pk4(b1.x * xb, b1.y * xb, b1.z * xb, b1.w * xb);
    reinterpret_cast<uint2*>(f8 + (size_t)i * D_DIM)[tid] = oa;
    reinterpret_cast<uint2*>(f8 + (size_t)(i + B_SZ) * D_DIM)[tid] = ob;
}

// ---------- kernel 2: everything GEMM — 576 thr = 8 GEMM waves + 1 copy wave ----------
// blocks 0..1023: 128x256 symmetric-Gram jobs (R10 loop); 1024..1279: 16x256 slivers.
// Wave 8 in every block streams the s/u/tau->out copy, matching the 32-barrier cadence.
__global__ __launch_bounds__(576) void kbig(
        const unsigned char* __restrict__ f8,
        const float* __restrict__ tau_buf, const int* __restrict__ index,
        float* __restrict__ E, float* __restrict__ F,
        const float4* __restrict__ sIn, const float4* __restrict__ uIn,
        const float4* __restrict__ tIn, float* __restrict__ out) {
    const int raw = (int)blockIdx.x;
    const int tid = threadIdx.x;
    const int lane = tid & 63;
    const int w = tid >> 6;            // wave 0..8
    const int l15 = lane & 15, lhi = lane >> 4;

    __shared__ alignas(16) unsigned char As[3][128 * 64];   // 8 KB each
    __shared__ alignas(16) unsigned char Bs[3][256 * 64];   // 16 KB each

    // ================= copy wave (all blocks) =================
    if (w == 8) {
        size_t g = (size_t)raw * 64 + lane;
        const size_t n4 = N_TOT / 4;
        const size_t str = (size_t)NBLK * 64;
        __builtin_amdgcn_s_barrier();                       // matches GEMM prologue barrier
        for (int t = 0; t < NT; ++t) {
#pragma unroll
            for (int k = 0; k < 2; ++k) {
                size_t i = g + (size_t)(2 * t + k) * str;
                if (i < n4) {
                    float4 vs = sIn[i], vu = uIn[i], vt = tIn[i];
                    *reinterpret_cast<float4u*>(out + 1 + 4 * i) = vs;
                    *reinterpret_cast<float4u*>(out + 1 + (size_t)N_TOT + 4 * i) = vu;
                    *reinterpret_cast<float4u*>(out + 1 + 2 * (size_t)N_TOT + 4 * i) = vt;
                }
            }
            if (t < NT - 1) __builtin_amdgcn_s_barrier();
        }
        return;
    }

    // read-side swizzle constants (shared by both GEMM paths)
    const int kx = (l15 >> 1) & 3;
    const int pk0 = (((lhi >> 1) ^ kx) * 16) + (lhi & 1) * 8;        // ks=0
    const int pk1 = ((((lhi >> 1) + 2) ^ kx) * 16) + (lhi & 1) * 8;  // ks=1
    const int rr = lane >> 2;
    const int sj = (lane & 3) ^ ((rr >> 1) & 3);

    if (raw < NJOB) {
        // ================= main 128x256 job (waves 0..7) =================
        const int bid = (raw & 7) * (NJOB / 8) + (raw >> 3);   // chunked XCD swizzle
        int C = (int)((sqrtf((float)(4 * bid + 1)) - 1.0f) * 0.5f);
        while (C * C + C > bid) --C;
        while ((C + 1) * (C + 1) + (C + 1) <= bid) ++C;
        const int R = bid - C * C - C;
        const int r0 = R * 128, c0 = C * 256;
        const int wr = w >> 2, wc = w & 3;

        f32x4 acc[4][4] = {};

        const size_t gA  = (size_t)(r0 + w * 16 + rr) * D_DIM + sj * 16;
        const size_t gB0 = (size_t)(c0 + w * 32 + rr) * D_DIM + sj * 16;
        const size_t gB1 = gB0 + 16 * D_DIM;
        const int lA = w * 1024, lB0 = w * 2048, lB1 = w * 2048 + 1024;

#define STAGEM(buf, t)                                             \
    do {                                                           \
        size_t k_ = (size_t)(t) * 64u;                             \
        gload_lds16(f8 + gA + k_,  &As[buf][lA]);                  \
        gload_lds16(f8 + gB0 + k_, &Bs[buf][lB0]);                 \
        gload_lds16(f8 + gB1 + k_, &Bs[buf][lB1]);                 \
    } while (0)

        STAGEM(0, 0);
        STAGEM(1, 1);
        asm volatile("s_waitcnt vmcnt(3)" ::: "memory");
        __builtin_amdgcn_sched_barrier(0);
        __builtin_amdgcn_s_barrier();

        int bufc = 0;
        for (int t = 0; t < NT; ++t) {
            if (t + 2 < NT) {
                int bw = (bufc >= 1) ? bufc - 1 : 2;     // (bufc+2)%3
                STAGEM(bw, t + 2);
            }
            const unsigned char* __restrict__ A_l = &As[bufc][0];
            const unsigned char* __restrict__ B_l = &Bs[bufc][0];
            long af[4][2], bfr[4][2];
#pragma unroll
            for (int m = 0; m < 4; ++m) {
                int rowb = (wr * 64 + m * 16 + l15) * 64;
                af[m][0] = *reinterpret_cast<const long*>(&A_l[rowb + pk0]);
                af[m][1] = *reinterpret_cast<const long*>(&A_l[rowb + pk1]);
            }
#pragma unroll
            for (int n = 0; n < 4; ++n) {
                int rowb = (wc * 64 + n * 16 + l15) * 64;
                bfr[n][0] = *reinterpret_cast<const long*>(&B_l[rowb + pk0]);
                bfr[n][1] = *reinterpret_cast<const long*>(&B_l[rowb + pk1]);
            }
            __builtin_amdgcn_s_setprio(1);
#pragma unroll
            for (int m = 0; m < 4; ++m)
#pragma unroll
                for (int n = 0; n < 4; ++n) {
                    acc[m][n] = __builtin_amdgcn_mfma_f32_16x16x32_fp8_fp8(af[m][0], bfr[n][0], acc[m][n], 0, 0, 0);
                    acc[m][n] = __builtin_amdgcn_mfma_f32_16x16x32_fp8_fp8(af[m][1], bfr[n][1], acc[m][n], 0, 0, 0);
                }
            __builtin_amdgcn_s_setprio(0);
            if (t < NT - 2) {
                asm volatile("s_waitcnt vmcnt(3)" ::: "memory");
            } else if (t == NT - 2) {
                asm volatile("s_waitcnt vmcnt(0)" ::: "memory");
            }
            __builtin_amdgcn_sched_barrier(0);
            if (t < NT - 1) __builtin_amdgcn_s_barrier();
            bufc = (bufc == 2) ? 0 : bufc + 1;
        }
#undef STAGEM

        // epilogue: direct (row tau) + transposed (col tau)
#pragma unroll
        for (int m = 0; m < 4; ++m) {
#pragma unroll
            for (int r = 0; r < 4; ++r) {
                int row_g = r0 + wr * 64 + m * 16 + lhi * 4 + r;
                float it = 1.0f / tau_buf[index[row_g & (B_SZ - 1)]];
                float e = 0.f, f = 0.f;
#pragma unroll
                for (int n = 0; n < 4; ++n) {
                    int col_g = c0 + wc * 64 + n * 16 + l15;
                    float v = acc[m][n][r] * INV_SC;
                    if (col_g > row_g && (((row_g ^ col_g) & (B_SZ - 1)) != 0)) {
                        float ex = __expf(v * it);
                        e += ex;
                        f += ex * v;
                    }
                }
#pragma unroll
                for (int off = 1; off < 16; off <<= 1) {
                    e += __shfl_xor(e, off, 64);
                    f += __shfl_xor(f, off, 64);
                }
                if (l15 == 0) {
                    atomicAdd(&E[row_g], e);
                    atomicAdd(&F[row_g], f);
                }
            }
        }
#pragma unroll
        for (int n = 0; n < 4; ++n) {
            int colT = c0 + wc * 64 + n * 16 + l15;
            float it = 1.0f / tau_buf[index[colT & (B_SZ - 1)]];
            float e = 0.f, f = 0.f;
#pragma unroll
            for (int m = 0; m < 4; ++m) {
#pragma unroll
                for (int r = 0; r < 4; ++r) {
                    int row_g = r0 + wr * 64 + m * 16 + lhi * 4 + r;
                    float v = acc[m][n][r] * INV_SC;
                    if (colT > row_g && (((row_g ^ colT) & (B_SZ - 1)) != 0)) {
                        float ex = __expf(v * it);
                        e += ex;
                        f += ex * v;
                    }
                }
            }
            e += __shfl_xor(e, 16, 64);
            f += __shfl_xor(f, 16, 64);
            e += __shfl_xor(e, 32, 64);
            f += __shfl_xor(f, 32, 64);
            if (lhi == 0) {
                atomicAdd(&E[colT], e);
                atomicAdd(&F[colT], f);
            }
        }
    } else {
        // ================= sliver: 16x256 (waves 0..7) =================
        const int sb = raw - NJOB;               // 0..255
        const int R = 32 + (sb >> 3);            // 32..63
        const int sv = sb & 7;
        const int r0 = R * 128 + sv * 16;
        const int c0 = 31 * 256;

        f32x4 acc[2] = {};

        const size_t gA  = (size_t)(r0 + rr) * D_DIM + sj * 16;          // same for all waves
        const size_t gB0 = (size_t)(c0 + w * 32 + rr) * D_DIM + sj * 16;
        const size_t gB1 = gB0 + 16 * D_DIM;
        const int lB0 = w * 2048, lB1 = w * 2048 + 1024;

#define STAGES(buf, t)                                             \
    do {                                                           \
        size_t k_ = (size_t)(t) * 64u;                             \
        gload_lds16(f8 + gA + k_,  &As[buf][0]);                   \
        gload_lds16(f8 + gB0 + k_, &Bs[buf][lB0]);                 \
        gload_lds16(f8 + gB1 + k_, &Bs[buf][lB1]);                 \
    } while (0)

        STAGES(0, 0);
        STAGES(1, 1);
        asm volatile("s_waitcnt vmcnt(3)" ::: "memory");
        __builtin_amdgcn_sched_barrier(0);
        __builtin_amdgcn_s_barrier();

        int bufc = 0;
        for (int t = 0; t < NT; ++t) {
            if (t + 2 < NT) {
                int bw = (bufc >= 1) ? bufc - 1 : 2;
                STAGES(bw, t + 2);
            }
            const unsigned char* __restrict__ A_l = &As[bufc][0];
            const unsigned char* __restrict__ B_l = &Bs[bufc][0];
            long af0, af1, bfr[2][2];
            {
                int rowb = l15 * 64;
                af0 = *reinterpret_cast<const long*>(&A_l[rowb + pk0]);
                af1 = *reinterpret_cast<const long*>(&A_l[rowb + pk1]);
            }
#pragma unroll
            for (int n = 0; n < 2; ++n) {
                int rowb = (w * 32 + n * 16 + l15) * 64;
                bfr[n][0] = *reinterpret_cast<const long*>(&B_l[rowb + pk0]);
                bfr[n][1] = *reinterpret_cast<const long*>(&B_l[rowb + pk1]);
            }
            __builtin_amdgcn_s_setprio(1);
#pragma unroll
            for (int n = 0; n < 2; ++n) {
                acc[n] = __builtin_amdgcn_mfma_f32_16x16x32_fp8_fp8(af0, bfr[n][0], acc[n], 0, 0, 0);
                acc[n] = __builtin_amdgcn_mfma_f32_16x16x32_fp8_fp8(af1, bfr[n][1], acc[n], 0, 0, 0);
            }
            __builtin_amdgcn_s_setprio(0);
            if (t < NT - 2) {
                asm volatile("s_waitcnt vmcnt(3)" ::: "memory");
            } else if (t == NT - 2) {
                asm volatile("s_waitcnt vmcnt(0)" ::: "memory");
            }
            __builtin_amdgcn_sched_barrier(0);
            if (t < NT - 1) __builtin_amdgcn_s_barrier();
            bufc = (bufc == 2) ? 0 : bufc + 1;
        }
#undef STAGES

#pragma unroll
        for (int r = 0; r < 4; ++r) {
            int row_g = r0 + lhi * 4 + r;
            float it = 1.0f / tau_buf[index[row_g & (B_SZ - 1)]];
            float e = 0.f, f = 0.f;
#pragma unroll
            for (int n = 0; n < 2; ++n) {
                int col_g = c0 + w * 32 + n * 16 + l15;
                float v = acc[n][r] * INV_SC;
                if (col_g > row_g && (((row_g ^ col_g) & (B_SZ - 1)) != 0)) {
                    float ex = __expf(v * it);
                    e += ex;
                    f += ex * v;
                }
            }
#pragma unroll
            for (int off = 1; off < 16; off <<= 1) {
                e += __shfl_xor(e, off, 64);
                f += __shfl_xor(f, off, 64);
            }
            if (l15 == 0) {
                atomicAdd(&E[row_g], e);
                atomicAdd(&F[row_g], f);
            }
        }
#pragma unroll
        for (int n = 0; n < 2; ++n) {
            int colT = c0 + w * 32 + n * 16 + l15;
            float it = 1.0f / tau_buf[index[colT & (B_SZ - 1)]];
            float e = 0.f, f = 0.f;
#pragma unroll
            for (int r = 0; r < 4; ++r) {
                int row_g = r0 + lhi * 4 + r;
                float v = acc[n][r] * INV_SC;
                if (colT > row_g && (((row_g ^ colT) & (B_SZ - 1)) != 0)) {
                    float ex = __expf(v * it);
                    e += ex;
                    f += ex * v;
                }
            }
            e += __shfl_xor(e, 16, 64);
            f += __shfl_xor(f, 16, 64);
            e += __shfl_xor(e, 32, 64);
            f += __shfl_xor(f, 32, 64);
            if (lhi == 0) {
                atomicAdd(&E[colT], e);
                atomicAdd(&F[colT], f);
            }
        }
    }
}

// ---------- kernel 3: finalize per positive pair ----------
__global__ __launch_bounds__(64) void kfin(const float* __restrict__ E,
                                           const float* __restrict__ F,
                                           const float* __restrict__ posdot,
                                           const float* __restrict__ s,
                                           const float* __restrict__ tau_buf,
                                           const float* __restrict__ u_buf,
                                           const int* __restrict__ index,
                                           const int* __restrict__ epoch_p,
                                           float* __restrict__ out) {
    int i = blockIdx.x;     // [0, B)
    int lane = threadIdx.x; // [0, 64)
    int idx = index[i];
    bool dup = false;
    for (int j = i + 1 + lane; j < B_SZ; j += 64)
        if (index[j] == idx) dup = true;
    unsigned long long ball = __ballot(dup);

    if (lane == 0) {
        float e1 = E[i], f1 = F[i];
        float e2 = E[i + B_SZ], f2 = F[i + B_SZ];
        const float num_neg = 2.0f * B_SZ - 2.0f;
        float g1 = e1 / num_neg, g2 = e2 / num_neg;
        float s_old = s[idx];
        float tau_i = tau_buf[idx];
        float u_old = u_buf[idx];
        int ep = *epoch_p;
        float s1, s2;
        if (ep == 0) { s1 = g1; s2 = g2; }
        else { s1 = 0.2f * s_old + 0.8f * g1; s2 = 0.2f * s_old + 0.8f * g2; }
        float pos = posdot[i];
        float l1 = f1 / (s1 * num_neg) - pos;
        float l2 = f2 / (s2 * num_neg) - pos;
        atomicAdd(out, (l1 + l2) * (1.0f / B_SZ));
        float gt1 = logf(s1) + RHO - f1 / (tau_i * s1 * num_neg);
        float gt2 = logf(s2) + RHO - f2 / (tau_i * s2 * num_neg);
        float gt = 0.5f * (gt1 + gt2);
        gt = fminf(fmaxf(gt, -3.0f), 3.0f);
        float u_new = 0.1f * u_old + 0.9f * gt;
        float tau_new = fminf(fmaxf(tau_i - 0.001f * u_new, 0.05f), 1.0f);
        if (ball == 0ULL) {  // winner (numpy last-wins)
            out[1 + (size_t)idx] = 0.5f * (s1 + s2);
            out[1 + (size_t)N_TOT + idx] = u_new;
            out[1 + 2 * (size_t)N_TOT + idx] = tau_new;
        }
    }
}

extern "C" void kernel_launch(void* const* d_in, const int* in_sizes, int n_in,
                              void* d_out, int out_size, void* d_ws, size_t ws_size,
                              hipStream_t stream) {
    const float* features = (const float*)d_in[0];
    const float* s        = (const float*)d_in[1];
    const float* tau_buf  = (const float*)d_in[2];
    const float* u_buf    = (const float*)d_in[3];
    const int*   index    = (const int*)d_in[4];
    const int*   epoch    = (const int*)d_in[5];
    float* out = (float*)d_out;
    char* ws = (char*)d_ws;

    // workspace layout
    unsigned char* f8     = (unsigned char*)(ws);        // 8192*2048 = 16,777,216 B
    float*         E      = (float*)(ws + 16777216);     // 32 KB
    float*         F      = (float*)(ws + 16809984);     // 32 KB (contiguous after E)
    float*         posdot = (float*)(ws + 16842752);     // 16 KB

    knorm2<<<B_SZ, 256, 0, stream>>>(features, f8, posdot, E, out);
    kbig<<<NBLK, 576, 0, stream>>>(f8, tau_buf, index, E, F,
                                   (const float4*)s, (const float4*)u_buf,
                                   (const float4*)tau_buf, out);
    kfin<<<B_SZ, 64, 0, stream>>>(E, F, posdot, s, tau_buf, u_buf, index, epoch, out);
}

// Round 13
// 257.458 us; speedup vs baseline: 1.4574x; 1.4574x over previous
//
#include <hip/hip_runtime.h>
#include <hip/hip_bf16.h>
#include <stdint.h>

#define B_SZ   4096
#define TWO_B  8192
#define D_DIM  2048
#define N_TOT  15000000
#define RHO    0.8f
#define NT     32         // 2048 / 64 K-tiles (fp8, BK=64)
#define NJOB   1024       // main jobs: cells 0..1023 (C-major over upper-tri 128x256 cells)
#define NSLV   256        // 32 remaining cells (C=31, R=32..63) x 8 slivers of 16x256
#define NBLK   1280       // NJOB + NSLV
#define INV_SC (1.0f/256.0f)   // undo the 16x16 input pre-scale

typedef __attribute__((ext_vector_type(4))) float f32x4;
typedef float4 __attribute__((aligned(4))) float4u;

// ---------- helpers ----------
__device__ __forceinline__ float waveReduceSum(float v) {
#pragma unroll
    for (int off = 32; off >= 1; off >>= 1) v += __shfl_down(v, off, 64);
    return v;
}
__device__ __forceinline__ void gload_lds16(const void* g, void* l) {
    __builtin_amdgcn_global_load_lds(
        (const __attribute__((address_space(1))) void*)(uintptr_t)g,
        (__attribute__((address_space(3))) void*)(uintptr_t)l,
        16, 0, 0);
}
__device__ __forceinline__ unsigned pk4(float a, float b, float c, float d) {
    int r = 0;
    r = __builtin_amdgcn_cvt_pk_fp8_f32(a, b, r, false);   // bytes 0,1
    r = __builtin_amdgcn_cvt_pk_fp8_f32(c, d, r, true);    // bytes 2,3
    return (unsigned)r;
}

// ---------- kernel 1: paired normalize -> fp8 e4m3 (x16), + pos dot, + zero E/F/loss ----------
__global__ __launch_bounds__(256) void knorm2(const float* __restrict__ feat,
                                              unsigned char* __restrict__ f8,
                                              float* __restrict__ posdot,
                                              float* __restrict__ EF,
                                              float* __restrict__ out) {
    int i = blockIdx.x;           // [0, B)
    int tid = threadIdx.x;
    // fused zeroing: E and F (2*TWO_B floats = 4096 float4) by blocks 0..15; loss by block 16
    if (i < 16) {
        float4 z = make_float4(0.f, 0.f, 0.f, 0.f);
        reinterpret_cast<float4*>(EF)[i * 256 + tid] = z;
    }
    if (i == 16 && tid == 0) out[0] = 0.f;

    const float4* ra = reinterpret_cast<const float4*>(feat + (size_t)i * D_DIM);
    const float4* rb = reinterpret_cast<const float4*>(feat + (size_t)(i + B_SZ) * D_DIM);
    float4 a0 = ra[tid * 2], a1 = ra[tid * 2 + 1];
    float4 b0 = rb[tid * 2], b1 = rb[tid * 2 + 1];
    float sa = a0.x*a0.x + a0.y*a0.y + a0.z*a0.z + a0.w*a0.w
             + a1.x*a1.x + a1.y*a1.y + a1.z*a1.z + a1.w*a1.w;
    float sb = b0.x*b0.x + b0.y*b0.y + b0.z*b0.z + b0.w*b0.w
             + b1.x*b1.x + b1.y*b1.y + b1.z*b1.z + b1.w*b1.w;
    float dp = a0.x*b0.x + a0.y*b0.y + a0.z*b0.z + a0.w*b0.w
             + a1.x*b1.x + a1.y*b1.y + a1.z*b1.z + a1.w*b1.w;
    sa = waveReduceSum(sa);
    sb = waveReduceSum(sb);
    dp = waveReduceSum(dp);
    __shared__ float wsum[3][4];
    if ((tid & 63) == 0) {
        int wv = tid >> 6;
        wsum[0][wv] = sa; wsum[1][wv] = sb; wsum[2][wv] = dp;
    }
    __syncthreads();
    float ta = wsum[0][0] + wsum[0][1] + wsum[0][2] + wsum[0][3];
    float tb = wsum[1][0] + wsum[1][1] + wsum[1][2] + wsum[1][3];
    float td = wsum[2][0] + wsum[2][1] + wsum[2][2] + wsum[2][3];
    float ia = 1.0f / fmaxf(sqrtf(ta), 1e-12f);
    float ib = 1.0f / fmaxf(sqrtf(tb), 1e-12f);
    if (tid == 0) posdot[i] = td * ia * ib;
    float xa = ia * 16.0f, xb = ib * 16.0f;   // pre-scale for e4m3 dynamic range
    uint2 oa, ob;
    oa.x = pk4(a0.x * xa, a0.y * xa, a0.z * xa, a0.w * xa);
    oa.y = pk4(a1.x * xa, a1.y * xa, a1.z * xa, a1.w * xa);
    ob.x = pk4(b0.x * xb, b0.y * xb, b0.z * xb, b0.w * xb);
    ob.y = pk4(b1.x * xb, b1.y * xb, b1.z * xb, b1.w * xb);
    reinterpret_cast<uint2*>(f8 + (size_t)i * D_DIM)[tid] = oa;
    reinterpret_cast<uint2*>(f8 + (size_t)(i + B_SZ) * D_DIM)[tid] = ob;
}

// ---------- kernel 2: fused GEMM (main 128x256 jobs + 16x256 slivers) ----------
// 512 thr / 8 waves. R10 inner loop. Copy of s/u/tau spread at K-loop boundaries
// t=8/16/24 (main jobs) or at end (slivers); each block moves 6 grid-stride
// float4-triples per thread.
__global__ __launch_bounds__(512, 4) void kbig(
        const unsigned char* __restrict__ f8,
        const float* __restrict__ tau_buf, const int* __restrict__ index,
        float* __restrict__ E, float* __restrict__ F,
        const float4* __restrict__ sIn, const float4* __restrict__ uIn,
        const float4* __restrict__ tIn, float* __restrict__ out) {
    const int raw = (int)blockIdx.x;
    const int tid = threadIdx.x;
    const int lane = tid & 63;
    const int w = tid >> 6;            // wave 0..7
    const int l15 = lane & 15, lhi = lane >> 4;

    __shared__ alignas(16) unsigned char As[3][128 * 64];   // 8 KB each
    __shared__ alignas(16) unsigned char Bs[3][256 * 64];   // 16 KB each

    // copy geometry (all blocks share the grid-stride range)
    const size_t n4 = N_TOT / 4;
    const size_t cstr = (size_t)NBLK * 512;
    const size_t cg = (size_t)raw * 512 + tid;

#define COPY2(kk)                                                              \
    do {                                                                       \
        _Pragma("unroll") for (int q = 0; q < 2; ++q) {                        \
            size_t ci = cg + (size_t)(2 * (kk) + q) * cstr;                    \
            if (ci < n4) {                                                     \
                float4 vs = sIn[ci], vu = uIn[ci], vt = tIn[ci];               \
                *reinterpret_cast<float4u*>(out + 1 + 4 * ci) = vs;            \
                *reinterpret_cast<float4u*>(out + 1 + (size_t)N_TOT + 4 * ci) = vu; \
                *reinterpret_cast<float4u*>(out + 1 + 2 * (size_t)N_TOT + 4 * ci) = vt; \
            }                                                                  \
        }                                                                      \
    } while (0)

    // read-side swizzle constants (shared by both GEMM paths)
    const int kx = (l15 >> 1) & 3;
    const int pk0 = (((lhi >> 1) ^ kx) * 16) + (lhi & 1) * 8;        // ks=0
    const int pk1 = ((((lhi >> 1) + 2) ^ kx) * 16) + (lhi & 1) * 8;  // ks=1
    const int rr = lane >> 2;
    const int sj = (lane & 3) ^ ((rr >> 1) & 3);

    if (raw < NJOB) {
        // ================= main 128x256 job =================
        const int bid = (raw & 7) * (NJOB / 8) + (raw >> 3);   // chunked XCD swizzle
        int C = (int)((sqrtf((float)(4 * bid + 1)) - 1.0f) * 0.5f);
        while (C * C + C > bid) --C;
        while ((C + 1) * (C + 1) + (C + 1) <= bid) ++C;
        const int R = bid - C * C - C;
        const int r0 = R * 128, c0 = C * 256;
        const int wr = w >> 2, wc = w & 3;

        f32x4 acc[4][4] = {};

        const size_t gA  = (size_t)(r0 + w * 16 + rr) * D_DIM + sj * 16;
        const size_t gB0 = (size_t)(c0 + w * 32 + rr) * D_DIM + sj * 16;
        const size_t gB1 = gB0 + 16 * D_DIM;
        const int lA = w * 1024, lB0 = w * 2048, lB1 = w * 2048 + 1024;

#define STAGEM(buf, t)                                             \
    do {                                                           \
        size_t k_ = (size_t)(t) * 64u;                             \
        gload_lds16(f8 + gA + k_,  &As[buf][lA]);                  \
        gload_lds16(f8 + gB0 + k_, &Bs[buf][lB0]);                 \
        gload_lds16(f8 + gB1 + k_, &Bs[buf][lB1]);                 \
    } while (0)

        STAGEM(0, 0);
        STAGEM(1, 1);
        asm volatile("s_waitcnt vmcnt(3)" ::: "memory");
        __builtin_amdgcn_sched_barrier(0);
        __builtin_amdgcn_s_barrier();

        int bufc = 0;
        for (int t = 0; t < NT; ++t) {
            const bool cpb = (t == 8) || (t == 16) || (t == 24);
            if (cpb) {
                // copy chunk; its load-use waits drain stage(t+1) too (FIFO vmcnt),
                // so the bottom vmcnt(3) is skipped this iteration.
                COPY2((t >> 3) - 1);
            }
            if (t + 2 < NT) {
                int bw = (bufc >= 1) ? bufc - 1 : 2;     // (bufc+2)%3
                STAGEM(bw, t + 2);
            }
            const unsigned char* __restrict__ A_l = &As[bufc][0];
            const unsigned char* __restrict__ B_l = &Bs[bufc][0];
            long af[4][2], bfr[4][2];
#pragma unroll
            for (int m = 0; m < 4; ++m) {
                int rowb = (wr * 64 + m * 16 + l15) * 64;
                af[m][0] = *reinterpret_cast<const long*>(&A_l[rowb + pk0]);
                af[m][1] = *reinterpret_cast<const long*>(&A_l[rowb + pk1]);
            }
#pragma unroll
            for (int n = 0; n < 4; ++n) {
                int rowb = (wc * 64 + n * 16 + l15) * 64;
                bfr[n][0] = *reinterpret_cast<const long*>(&B_l[rowb + pk0]);
                bfr[n][1] = *reinterpret_cast<const long*>(&B_l[rowb + pk1]);
            }
            __builtin_amdgcn_s_setprio(1);
#pragma unroll
            for (int m = 0; m < 4; ++m)
#pragma unroll
                for (int n = 0; n < 4; ++n) {
                    acc[m][n] = __builtin_amdgcn_mfma_f32_16x16x32_fp8_fp8(af[m][0], bfr[n][0], acc[m][n], 0, 0, 0);
                    acc[m][n] = __builtin_amdgcn_mfma_f32_16x16x32_fp8_fp8(af[m][1], bfr[n][1], acc[m][n], 0, 0, 0);
                }
            __builtin_amdgcn_s_setprio(0);
            if (!cpb) {
                if (t < NT - 2) {
                    asm volatile("s_waitcnt vmcnt(3)" ::: "memory");
                } else if (t == NT - 2) {
                    asm volatile("s_waitcnt vmcnt(0)" ::: "memory");
                }
                __builtin_amdgcn_sched_barrier(0);
            }
            if (t < NT - 1) __builtin_amdgcn_s_barrier();
            bufc = (bufc == 2) ? 0 : bufc + 1;
        }
#undef STAGEM

        // epilogue: direct (row tau) + transposed (col tau)
#pragma unroll
        for (int m = 0; m < 4; ++m) {
#pragma unroll
            for (int r = 0; r < 4; ++r) {
                int row_g = r0 + wr * 64 + m * 16 + lhi * 4 + r;
                float it = 1.0f / tau_buf[index[row_g & (B_SZ - 1)]];
                float e = 0.f, f = 0.f;
#pragma unroll
                for (int n = 0; n < 4; ++n) {
                    int col_g = c0 + wc * 64 + n * 16 + l15;
                    float v = acc[m][n][r] * INV_SC;
                    if (col_g > row_g && (((row_g ^ col_g) & (B_SZ - 1)) != 0)) {
                        float ex = __expf(v * it);
                        e += ex;
                        f += ex * v;
                    }
                }
#pragma unroll
                for (int off = 1; off < 16; off <<= 1) {
                    e += __shfl_xor(e, off, 64);
                    f += __shfl_xor(f, off, 64);
                }
                if (l15 == 0) {
                    atomicAdd(&E[row_g], e);
                    atomicAdd(&F[row_g], f);
                }
            }
        }
#pragma unroll
        for (int n = 0; n < 4; ++n) {
            int colT = c0 + wc * 64 + n * 16 + l15;
            float it = 1.0f / tau_buf[index[colT & (B_SZ - 1)]];
            float e = 0.f, f = 0.f;
#pragma unroll
            for (int m = 0; m < 4; ++m) {
#pragma unroll
                for (int r = 0; r < 4; ++r) {
                    int row_g = r0 + wr * 64 + m * 16 + lhi * 4 + r;
                    float v = acc[m][n][r] * INV_SC;
                    if (colT > row_g && (((row_g ^ colT) & (B_SZ - 1)) != 0)) {
                        float ex = __expf(v * it);
                        e += ex;
                        f += ex * v;
                    }
                }
            }
            e += __shfl_xor(e, 16, 64);
            f += __shfl_xor(f, 16, 64);
            e += __shfl_xor(e, 32, 64);
            f += __shfl_xor(f, 32, 64);
            if (lhi == 0) {
                atomicAdd(&E[colT], e);
                atomicAdd(&F[colT], f);
            }
        }
    } else {
        // ================= sliver: 16x256 =================
        const int sb = raw - NJOB;               // 0..255
        const int R = 32 + (sb >> 3);            // 32..63
        const int sv = sb & 7;
        const int r0 = R * 128 + sv * 16;
        const int c0 = 31 * 256;

        f32x4 acc[2] = {};

        const size_t gA  = (size_t)(r0 + rr) * D_DIM + sj * 16;          // same for all waves
        const size_t gB0 = (size_t)(c0 + w * 32 + rr) * D_DIM + sj * 16;
        const size_t gB1 = gB0 + 16 * D_DIM;
        const int lB0 = w * 2048, lB1 = w * 2048 + 1024;

#define STAGES(buf, t)                                             \
    do {                                                           \
        size_t k_ = (size_t)(t) * 64u;                             \
        gload_lds16(f8 + gA + k_,  &As[buf][0]);                   \
        gload_lds16(f8 + gB0 + k_, &Bs[buf][lB0]);                 \
        gload_lds16(f8 + gB1 + k_, &Bs[buf][lB1]);                 \
    } while (0)

        STAGES(0, 0);
        STAGES(1, 1);
        asm volatile("s_waitcnt vmcnt(3)" ::: "memory");
        __builtin_amdgcn_sched_barrier(0);
        __builtin_amdgcn_s_barrier();

        int bufc = 0;
        for (int t = 0; t < NT; ++t) {
            if (t + 2 < NT) {
                int bw = (bufc >= 1) ? bufc - 1 : 2;
                STAGES(bw, t + 2);
            }
            const unsigned char* __restrict__ A_l = &As[bufc][0];
            const unsigned char* __restrict__ B_l = &Bs[bufc][0];
            long af0, af1, bfr[2][2];
            {
                int rowb = l15 * 64;
                af0 = *reinterpret_cast<const long*>(&A_l[rowb + pk0]);
                af1 = *reinterpret_cast<const long*>(&A_l[rowb + pk1]);
            }
#pragma unroll
            for (int n = 0; n < 2; ++n) {
                int rowb = (w * 32 + n * 16 + l15) * 64;
                bfr[n][0] = *reinterpret_cast<const long*>(&B_l[rowb + pk0]);
                bfr[n][1] = *reinterpret_cast<const long*>(&B_l[rowb + pk1]);
            }
            __builtin_amdgcn_s_setprio(1);
#pragma unroll
            for (int n = 0; n < 2; ++n) {
                acc[n] = __builtin_amdgcn_mfma_f32_16x16x32_fp8_fp8(af0, bfr[n][0], acc[n], 0, 0, 0);
                acc[n] = __builtin_amdgcn_mfma_f32_16x16x32_fp8_fp8(af1, bfr[n][1], acc[n], 0, 0, 0);
            }
            __builtin_amdgcn_s_setprio(0);
            if (t < NT - 2) {
                asm volatile("s_waitcnt vmcnt(3)" ::: "memory");
            } else if (t == NT - 2) {
                asm volatile("s_waitcnt vmcnt(0)" ::: "memory");
            }
            __builtin_amdgcn_sched_barrier(0);
            if (t < NT - 1) __builtin_amdgcn_s_barrier();
            bufc = (bufc == 2) ? 0 : bufc + 1;
        }
#undef STAGES

#pragma unroll
        for (int r = 0; r < 4; ++r) {
            int row_g = r0 + lhi * 4 + r;
            float it = 1.0f / tau_buf[index[row_g & (B_SZ - 1)]];
            float e = 0.f, f = 0.f;
#pragma unroll
            for (int n = 0; n < 2; ++n) {
                int col_g = c0 + w * 32 + n * 16 + l15;
                float v = acc[n][r] * INV_SC;
                if (col_g > row_g && (((row_g ^ col_g) & (B_SZ - 1)) != 0)) {
                    float ex = __expf(v * it);
                    e += ex;
                    f += ex * v;
                }
            }
#pragma unroll
            for (int off = 1; off < 16; off <<= 1) {
                e += __shfl_xor(e, off, 64);
                f += __shfl_xor(f, off, 64);
            }
            if (l15 == 0) {
                atomicAdd(&E[row_g], e);
                atomicAdd(&F[row_g], f);
            }
        }
#pragma unroll
        for (int n = 0; n < 2; ++n) {
            int colT = c0 + w * 32 + n * 16 + l15;
            float it = 1.0f / tau_buf[index[colT & (B_SZ - 1)]];
            float e = 0.f, f = 0.f;
#pragma unroll
            for (int r = 0; r < 4; ++r) {
                int row_g = r0 + lhi * 4 + r;
                float v = acc[n][r] * INV_SC;
                if (colT > row_g && (((row_g ^ colT) & (B_SZ - 1)) != 0)) {
                    float ex = __expf(v * it);
                    e += ex;
                    f += ex * v;
                }
            }
            e += __shfl_xor(e, 16, 64);
            f += __shfl_xor(f, 16, 64);
            e += __shfl_xor(e, 32, 64);
            f += __shfl_xor(f, 32, 64);
            if (lhi == 0) {
                atomicAdd(&E[colT], e);
                atomicAdd(&F[colT], f);
            }
        }

        // sliver copy share (tail-fill)
        COPY2(0); COPY2(1); COPY2(2);
    }
#undef COPY2
}

// ---------- kernel 3: finalize per positive pair ----------
__global__ __launch_bounds__(64) void kfin(const float* __restrict__ E,
                                           const float* __restrict__ F,
                                           const float* __restrict__ posdot,
                                           const float* __restrict__ s,
                                           const float* __restrict__ tau_buf,
                                           const float* __restrict__ u_buf,
                                           const int* __restrict__ index,
                                           const int* __restrict__ epoch_p,
                                           float* __restrict__ out) {
    int i = blockIdx.x;     // [0, B)
    int lane = threadIdx.x; // [0, 64)
    int idx = index[i];
    bool dup = false;
    for (int j = i + 1 + lane; j < B_SZ; j += 64)
        if (index[j] == idx) dup = true;
    unsigned long long ball = __ballot(dup);

    if (lane == 0) {
        float e1 = E[i], f1 = F[i];
        float e2 = E[i + B_SZ], f2 = F[i + B_SZ];
        const float num_neg = 2.0f * B_SZ - 2.0f;
        float g1 = e1 / num_neg, g2 = e2 / num_neg;
        float s_old = s[idx];
        float tau_i = tau_buf[idx];
        float u_old = u_buf[idx];
        int ep = *epoch_p;
        float s1, s2;
        if (ep == 0) { s1 = g1; s2 = g2; }
        else { s1 = 0.2f * s_old + 0.8f * g1; s2 = 0.2f * s_old + 0.8f * g2; }
        float pos = posdot[i];
        float l1 = f1 / (s1 * num_neg) - pos;
        float l2 = f2 / (s2 * num_neg) - pos;
        atomicAdd(out, (l1 + l2) * (1.0f / B_SZ));
        float gt1 = logf(s1) + RHO - f1 / (tau_i * s1 * num_neg);
        float gt2 = logf(s2) + RHO - f2 / (tau_i * s2 * num_neg);
        float gt = 0.5f * (gt1 + gt2);
        gt = fminf(fmaxf(gt, -3.0f), 3.0f);
        float u_new = 0.1f * u_old + 0.9f * gt;
        float tau_new = fminf(fmaxf(tau_i - 0.001f * u_new, 0.05f), 1.0f);
        if (ball == 0ULL) {  // winner (numpy last-wins)
            out[1 + (size_t)idx] = 0.5f * (s1 + s2);
            out[1 + (size_t)N_TOT + idx] = u_new;
            out[1 + 2 * (size_t)N_TOT + idx] = tau_new;
        }
    }
}

extern "C" void kernel_launch(void* const* d_in, const int* in_sizes, int n_in,
                              void* d_out, int out_size, void* d_ws, size_t ws_size,
                              hipStream_t stream) {
    const float* features = (const float*)d_in[0];
    const float* s        = (const float*)d_in[1];
    const float* tau_buf  = (const float*)d_in[2];
    const float* u_buf    = (const float*)d_in[3];
    const int*   index    = (const int*)d_in[4];
    const int*   epoch    = (const int*)d_in[5];
    float* out = (float*)d_out;
    char* ws = (char*)d_ws;

    // workspace layout
    unsigned char* f8     = (unsigned char*)(ws);        // 8192*2048 = 16,777,216 B
    float*         E      = (float*)(ws + 16777216);     // 32 KB
    float*         F      = (float*)(ws + 16809984);     // 32 KB (contiguous after E)
    float*         posdot = (float*)(ws + 16842752);     // 16 KB

    knorm2<<<B_SZ, 256, 0, stream>>>(features, f8, posdot, E, out);
    kbig<<<NBLK, 512, 0, stream>>>(f8, tau_buf, index, E, F,
                                   (const float4*)s, (const float4*)u_buf,
                                   (const float4*)tau_buf, out);
    kfin<<<B_SZ, 64, 0, stream>>>(E, F, posdot, s, tau_buf, u_buf, index, epoch, out);
}